// Round 2
// baseline (317.426 us; speedup 1.0000x reference)
//
#include <hip/hip_runtime.h>
#include <hip/hip_bf16.h>

// Problem constants (B=2,S=2048 -> T=4096 tokens), H=1024, F=512, E=8, top-2.
#define T_TOK    4096
#define H_DIM    1024
#define F_DIM    512
#define N_EXP    8
#define N_ASSIGN 8192          // T_TOK * 2
#define BM 64
#define BN 64
#define BK 64
#define LDK 72                 // LDS K stride (+8 bf16 = +16B pad; 144B row = 16B-aligned)
#define MAX_TILES 160
#define GRID_MT   136          // worst-case sum_e ceil(Ne/64) <= 135

typedef __bf16 bf16x8 __attribute__((ext_vector_type(8)));
typedef float  f32x4  __attribute__((ext_vector_type(4)));

#define MFMA16(a, b, c) __builtin_amdgcn_mfma_f32_16x16x32_bf16((a), (b), (c), 0, 0, 0)

// ---------------------------------------------------------------------------
// Routing: 1 wave = 1 token. Fuses x fp32->bf16 conversion (wave-contiguous
// bf16x8 stores). Wr (32 KB) read straight from global -- L2-resident.
// No LDS, no barriers: 16 waves/CU hides latency (was 4 waves/CU, 100us).
// ---------------------------------------------------------------------------
__global__ __launch_bounds__(256) void routing_kernel(
    const float* __restrict__ x, const float* __restrict__ Wr,
    __bf16* __restrict__ xb, int* __restrict__ top_e, float* __restrict__ top_w,
    int* __restrict__ cnt)
{
    int wave = threadIdx.x >> 6, lane = threadIdx.x & 63;
    int t = blockIdx.x * 4 + wave;
    const float* xrow = x + (size_t)t * H_DIM;
    __bf16* xbrow = xb + (size_t)t * H_DIM;

    float part[N_EXP];
#pragma unroll
    for (int e = 0; e < N_EXP; ++e) part[e] = 0.f;

#pragma unroll
    for (int half = 0; half < 2; ++half) {
        int h0 = half * 512 + lane * 8;              // wave covers 512 contiguous
        float4 v0 = *(const float4*)(xrow + h0);
        float4 v1 = *(const float4*)(xrow + h0 + 4);
        float xs[8] = {v0.x, v0.y, v0.z, v0.w, v1.x, v1.y, v1.z, v1.w};
        bf16x8 bv;
#pragma unroll
        for (int i = 0; i < 8; ++i) bv[i] = (__bf16)xs[i];
        *(bf16x8*)(xbrow + h0) = bv;                 // 16B/lane, wave-contiguous
#pragma unroll
        for (int i = 0; i < 8; ++i) {
            const float4* wr = (const float4*)(Wr + (size_t)(h0 + i) * N_EXP);
            float4 w0 = wr[0], w1 = wr[1];
            part[0] += xs[i] * w0.x; part[1] += xs[i] * w0.y;
            part[2] += xs[i] * w0.z; part[3] += xs[i] * w0.w;
            part[4] += xs[i] * w1.x; part[5] += xs[i] * w1.y;
            part[6] += xs[i] * w1.z; part[7] += xs[i] * w1.w;
        }
    }
#pragma unroll
    for (int m = 1; m < 64; m <<= 1) {
#pragma unroll
        for (int e = 0; e < N_EXP; ++e) part[e] += __shfl_xor(part[e], m, 64);
    }
    if (lane == 0) {
        float v1 = -1e30f, v2 = -1e30f;
        int i1 = 0, i2 = 0;
#pragma unroll
        for (int e = 0; e < N_EXP; ++e) {
            float p = part[e];
            if (p > v1)      { v2 = v1; i2 = i1; v1 = p; i1 = e; }
            else if (p > v2) { v2 = p;  i2 = e; }
        }
        float w1 = 1.f / (1.f + __expf(v2 - v1));    // normalized top-2; softmax denom cancels
        top_e[t * 2]     = i1;  top_e[t * 2 + 1] = i2;
        top_w[t * 2]     = w1;  top_w[t * 2 + 1] = 1.f - w1;
        atomicAdd(&cnt[i1], 1);
        atomicAdd(&cnt[i2], 1);
    }
}

// ---------------------------------------------------------------------------
// Single-block: exclusive scan of counts, build M-tile worklist, scatter
// (token, weight) into expert-grouped perm/wts via LDS cursors.
// ---------------------------------------------------------------------------
__global__ __launch_bounds__(256) void schedule_scatter(
    const int* __restrict__ cnt, const int* __restrict__ top_e,
    const float* __restrict__ top_w,
    int* __restrict__ perm, float* __restrict__ wts,
    int* __restrict__ tile_e, int* __restrict__ tile_m0, int* __restrict__ tile_cnt,
    int* __restrict__ n_tiles)
{
    __shared__ int cur[N_EXP];
    if (threadIdx.x == 0) {
        int o = 0, nt = 0;
        for (int e = 0; e < N_EXP; ++e) {
            int ne = cnt[e];
            cur[e] = o;
            for (int m0 = 0; m0 < ne; m0 += BM) {
                tile_e[nt]   = e;
                tile_m0[nt]  = o + m0;
                tile_cnt[nt] = (ne - m0 < BM) ? (ne - m0) : BM;
                ++nt;
            }
            o += ne;
        }
        *n_tiles = nt;
    }
    __syncthreads();
    for (int t = threadIdx.x; t < T_TOK; t += 256) {
#pragma unroll
        for (int k = 0; k < 2; ++k) {
            int e = top_e[t * 2 + k];
            int slot = atomicAdd(&cur[e], 1);
            perm[slot] = t;
            wts[slot]  = top_w[t * 2 + k];
        }
    }
}

// ---------------------------------------------------------------------------
// Convert fp32 weights -> bf16 AND transpose to [N][K] (K-contiguous) so
// MFMA B fragments are 16B LDS vector loads.
//   z in [0,8):   Wg  [H][F] -> Wgt [F][H]
//   z in [8,16):  Wu  [H][F] -> Wut [F][H]
//   z in [16,24): Wd  [F][H] -> Wdt [H][F]
// ---------------------------------------------------------------------------
__global__ __launch_bounds__(256) void transpose_kernel(
    const float* __restrict__ Wg, const float* __restrict__ Wu, const float* __restrict__ Wd,
    __bf16* __restrict__ Wgt, __bf16* __restrict__ Wut, __bf16* __restrict__ Wdt)
{
    int z = blockIdx.z;
    const float* src; __bf16* dst; int R, C;
    if (z < 8)       { src = Wg + (size_t)z * H_DIM * F_DIM;        dst = Wgt + (size_t)z * H_DIM * F_DIM;        R = H_DIM; C = F_DIM; }
    else if (z < 16) { src = Wu + (size_t)(z - 8) * H_DIM * F_DIM;  dst = Wut + (size_t)(z - 8) * H_DIM * F_DIM;  R = H_DIM; C = F_DIM; }
    else             { src = Wd + (size_t)(z - 16) * F_DIM * H_DIM; dst = Wdt + (size_t)(z - 16) * F_DIM * H_DIM; R = F_DIM; C = H_DIM; }
    int c0 = blockIdx.x * 32, r0 = blockIdx.y * 32;
    if (c0 >= C || r0 >= R) return;
    __shared__ float tile[32][33];
    int tx = threadIdx.x & 31, ty = threadIdx.x >> 5;   // 32 x 8
#pragma unroll
    for (int i = 0; i < 4; ++i)
        tile[ty + 8 * i][tx] = src[(size_t)(r0 + ty + 8 * i) * C + c0 + tx];
    __syncthreads();
#pragma unroll
    for (int i = 0; i < 4; ++i)
        dst[(size_t)(c0 + ty + 8 * i) * R + r0 + tx] = (__bf16)tile[tx][ty + 8 * i];
}

// ---------------------------------------------------------------------------
// Grouped GEMM: act[slot][f] = silu(x@Wg) * (x@Wu) * combine_weight.
// Block = 256 thr (4 waves), tile 64(M-rows gathered via perm) x 64(F), K=H.
// Wave w computes 32x32 of gate AND up at (wm,wn).
// ---------------------------------------------------------------------------
__global__ __launch_bounds__(256) void gateup_kernel(
    const __bf16* __restrict__ xb, const __bf16* __restrict__ Wgt, const __bf16* __restrict__ Wut,
    const int* __restrict__ perm, const float* __restrict__ wts,
    const int* __restrict__ tile_e, const int* __restrict__ tile_m0, const int* __restrict__ tile_cnt,
    const int* __restrict__ n_tiles, __bf16* __restrict__ act)
{
    if ((int)blockIdx.x >= *n_tiles) return;
    int e = tile_e[blockIdx.x], m0 = tile_m0[blockIdx.x], mcnt = tile_cnt[blockIdx.x];
    int n0 = blockIdx.y * BN;

    __shared__ __bf16 As[BM][LDK];
    __shared__ __bf16 Bgs[BN][LDK];
    __shared__ __bf16 Bus[BN][LDK];
    __shared__ int   rowtok[BM];
    __shared__ float roww[BM];

    int tid = threadIdx.x;
    if (tid < BM) {
        int slot = m0 + ((tid < mcnt) ? tid : 0);
        rowtok[tid] = perm[slot];
        roww[tid]   = wts[slot];
    }
    __syncthreads();

    const __bf16* Wg_e = Wgt + (size_t)e * F_DIM * H_DIM;
    const __bf16* Wu_e = Wut + (size_t)e * F_DIM * H_DIM;

    int lr = tid >> 3, lc = tid & 7;          // staging: 32 rows x 8 chunks of 16B
    int wave = tid >> 6, lane = tid & 63;
    int wm = wave & 1, wn = wave >> 1;
    int quad = lane >> 4, l16 = lane & 15;

    f32x4 accg[2][2], accu[2][2];
#pragma unroll
    for (int a = 0; a < 2; ++a)
#pragma unroll
        for (int b = 0; b < 2; ++b) {
            accg[a][b] = (f32x4){0.f, 0.f, 0.f, 0.f};
            accu[a][b] = (f32x4){0.f, 0.f, 0.f, 0.f};
        }

    for (int k0 = 0; k0 < H_DIM; k0 += BK) {
#pragma unroll
        for (int p = 0; p < 2; ++p) {
            int r = lr + p * 32;
            *(bf16x8*)&As[r][lc * 8]  = *(const bf16x8*)(xb   + (size_t)rowtok[r] * H_DIM + k0 + lc * 8);
            *(bf16x8*)&Bgs[r][lc * 8] = *(const bf16x8*)(Wg_e + (size_t)(n0 + r) * H_DIM + k0 + lc * 8);
            *(bf16x8*)&Bus[r][lc * 8] = *(const bf16x8*)(Wu_e + (size_t)(n0 + r) * H_DIM + k0 + lc * 8);
        }
        __syncthreads();
#pragma unroll
        for (int kk = 0; kk < BK; kk += 32) {
            int kf = kk + quad * 8;
            bf16x8 a0 = *(const bf16x8*)&As[wm * 32 + l16][kf];
            bf16x8 a1 = *(const bf16x8*)&As[wm * 32 + 16 + l16][kf];
            bf16x8 g0 = *(const bf16x8*)&Bgs[wn * 32 + l16][kf];
            bf16x8 g1 = *(const bf16x8*)&Bgs[wn * 32 + 16 + l16][kf];
            bf16x8 u0 = *(const bf16x8*)&Bus[wn * 32 + l16][kf];
            bf16x8 u1 = *(const bf16x8*)&Bus[wn * 32 + 16 + l16][kf];
            accg[0][0] = MFMA16(a0, g0, accg[0][0]);
            accg[0][1] = MFMA16(a0, g1, accg[0][1]);
            accg[1][0] = MFMA16(a1, g0, accg[1][0]);
            accg[1][1] = MFMA16(a1, g1, accg[1][1]);
            accu[0][0] = MFMA16(a0, u0, accu[0][0]);
            accu[0][1] = MFMA16(a0, u1, accu[0][1]);
            accu[1][0] = MFMA16(a1, u0, accu[1][0]);
            accu[1][1] = MFMA16(a1, u1, accu[1][1]);
        }
        __syncthreads();
    }

    // Epilogue: C/D layout col=lane&15, row=quad*4+reg (m89-verified).
#pragma unroll
    for (int im = 0; im < 2; ++im) {
#pragma unroll
        for (int in = 0; in < 2; ++in) {
            int col = n0 + wn * 32 + in * 16 + l16;
#pragma unroll
            for (int r = 0; r < 4; ++r) {
                int rl = wm * 32 + im * 16 + quad * 4 + r;
                if (rl < mcnt) {
                    float g = accg[im][in][r];
                    float u = accu[im][in][r];
                    float s = g / (1.f + __expf(-g));         // silu
                    act[(size_t)(m0 + rl) * F_DIM + col] = (__bf16)(s * u * roww[rl]);
                }
            }
        }
    }
}

// ---------------------------------------------------------------------------
// Grouped down-proj: out[token][h] += act[slot][:] @ Wd[e][:][h]
// (combine weight already folded into act). fp32 native atomics, 2 writers max.
// ---------------------------------------------------------------------------
__global__ __launch_bounds__(256) void down_kernel(
    const __bf16* __restrict__ act, const __bf16* __restrict__ Wdt,
    const int* __restrict__ perm,
    const int* __restrict__ tile_e, const int* __restrict__ tile_m0, const int* __restrict__ tile_cnt,
    const int* __restrict__ n_tiles, float* __restrict__ out)
{
    if ((int)blockIdx.x >= *n_tiles) return;
    int e = tile_e[blockIdx.x], m0 = tile_m0[blockIdx.x], mcnt = tile_cnt[blockIdx.x];
    int n0 = blockIdx.y * BN;

    __shared__ __bf16 As[BM][LDK];
    __shared__ __bf16 Bs[BN][LDK];
    __shared__ int rowtok[BM];

    int tid = threadIdx.x;
    if (tid < BM) rowtok[tid] = perm[m0 + ((tid < mcnt) ? tid : 0)];
    __syncthreads();

    const __bf16* Wd_e = Wdt + (size_t)e * H_DIM * F_DIM;
    int lr = tid >> 3, lc = tid & 7;
    int wave = tid >> 6, lane = tid & 63;
    int wm = wave & 1, wn = wave >> 1;
    int quad = lane >> 4, l16 = lane & 15;

    f32x4 acc[2][2];
#pragma unroll
    for (int a = 0; a < 2; ++a)
#pragma unroll
        for (int b = 0; b < 2; ++b) acc[a][b] = (f32x4){0.f, 0.f, 0.f, 0.f};

    for (int k0 = 0; k0 < F_DIM; k0 += BK) {
#pragma unroll
        for (int p = 0; p < 2; ++p) {
            int r = lr + p * 32;
            int ar = m0 + ((r < mcnt) ? r : 0);
            *(bf16x8*)&As[r][lc * 8] = *(const bf16x8*)(act  + (size_t)ar * F_DIM + k0 + lc * 8);
            *(bf16x8*)&Bs[r][lc * 8] = *(const bf16x8*)(Wd_e + (size_t)(n0 + r) * F_DIM + k0 + lc * 8);
        }
        __syncthreads();
#pragma unroll
        for (int kk = 0; kk < BK; kk += 32) {
            int kf = kk + quad * 8;
            bf16x8 a0 = *(const bf16x8*)&As[wm * 32 + l16][kf];
            bf16x8 a1 = *(const bf16x8*)&As[wm * 32 + 16 + l16][kf];
            bf16x8 b0 = *(const bf16x8*)&Bs[wn * 32 + l16][kf];
            bf16x8 b1 = *(const bf16x8*)&Bs[wn * 32 + 16 + l16][kf];
            acc[0][0] = MFMA16(a0, b0, acc[0][0]);
            acc[0][1] = MFMA16(a0, b1, acc[0][1]);
            acc[1][0] = MFMA16(a1, b0, acc[1][0]);
            acc[1][1] = MFMA16(a1, b1, acc[1][1]);
        }
        __syncthreads();
    }

#pragma unroll
    for (int im = 0; im < 2; ++im) {
#pragma unroll
        for (int in = 0; in < 2; ++in) {
            int col = n0 + wn * 32 + in * 16 + l16;
#pragma unroll
            for (int r = 0; r < 4; ++r) {
                int rl = wm * 32 + im * 16 + quad * 4 + r;
                if (rl < mcnt)
                    unsafeAtomicAdd(out + (size_t)rowtok[rl] * H_DIM + col, acc[im][in][r]);
            }
        }
    }
}

// ---------------------------------------------------------------------------
extern "C" void kernel_launch(void* const* d_in, const int* in_sizes, int n_in,
                              void* d_out, int out_size, void* d_ws, size_t ws_size,
                              hipStream_t stream)
{
    const float* x  = (const float*)d_in[0];
    const float* Wr = (const float*)d_in[1];
    const float* Wg = (const float*)d_in[2];
    const float* Wu = (const float*)d_in[3];
    const float* Wd = (const float*)d_in[4];
    float* out = (float*)d_out;

    char* ws = (char*)d_ws;
    size_t off = 0;
    auto carve = [&](size_t bytes) {
        char* p = ws + off;
        off = (off + bytes + 255) & ~(size_t)255;
        return p;
    };
    __bf16* xb   = (__bf16*)carve((size_t)T_TOK * H_DIM * 2);            // 8 MB
    __bf16* Wgt  = (__bf16*)carve((size_t)N_EXP * H_DIM * F_DIM * 2);    // 8 MB
    __bf16* Wut  = (__bf16*)carve((size_t)N_EXP * H_DIM * F_DIM * 2);    // 8 MB
    __bf16* Wdt  = (__bf16*)carve((size_t)N_EXP * H_DIM * F_DIM * 2);    // 8 MB
    __bf16* act  = (__bf16*)carve((size_t)N_ASSIGN * F_DIM * 2);         // 8 MB
    int*   top_e = (int*)carve((size_t)T_TOK * 2 * sizeof(int));
    float* top_w = (float*)carve((size_t)T_TOK * 2 * sizeof(float));
    int*   perm  = (int*)carve((size_t)N_ASSIGN * sizeof(int));
    float* wts   = (float*)carve((size_t)N_ASSIGN * sizeof(float));
    int*   cnt   = (int*)carve(N_EXP * sizeof(int));
    int*   tl_e  = (int*)carve(MAX_TILES * sizeof(int));
    int*   tl_m0 = (int*)carve(MAX_TILES * sizeof(int));
    int*   tl_cn = (int*)carve(MAX_TILES * sizeof(int));
    int*   n_til = (int*)carve(sizeof(int));

    hipMemsetAsync(cnt, 0, N_EXP * sizeof(int), stream);
    hipMemsetAsync(d_out, 0, (size_t)out_size * sizeof(float), stream);

    routing_kernel<<<T_TOK / 4, 256, 0, stream>>>(x, Wr, xb, top_e, top_w, cnt);
    schedule_scatter<<<1, 256, 0, stream>>>(cnt, top_e, top_w, perm, wts,
                                            tl_e, tl_m0, tl_cn, n_til);
    transpose_kernel<<<dim3(32, 32, 24), 256, 0, stream>>>(Wg, Wu, Wd, Wgt, Wut, Wdt);
    gateup_kernel<<<dim3(GRID_MT, F_DIM / BN), 256, 0, stream>>>(
        xb, Wgt, Wut, perm, wts, tl_e, tl_m0, tl_cn, n_til, act);
    down_kernel<<<dim3(GRID_MT, H_DIM / BN), 256, 0, stream>>>(
        act, Wdt, perm, tl_e, tl_m0, tl_cn, n_til, out);
}

// Round 3
// 234.506 us; speedup vs baseline: 1.3536x; 1.3536x over previous
//
#include <hip/hip_runtime.h>
#include <hip/hip_bf16.h>

// Problem constants (B=2,S=2048 -> T=4096 tokens), H=1024, F=512, E=8, top-2.
#define T_TOK    4096
#define H_DIM    1024
#define F_DIM    512
#define N_EXP    8
#define N_ASSIGN 8192          // T_TOK * 2
#define BM 64
#define BN 64
#define BK 64
#define LDK 72                 // LDS K stride (+8 bf16 = +16B pad; 144B row = 16B-aligned)
#define MAX_TILES 160
#define GRID_MT   136          // worst-case sum_e ceil(Ne/64) <= 135

typedef __bf16 bf16x8 __attribute__((ext_vector_type(8)));
typedef float  f32x4  __attribute__((ext_vector_type(4)));

#define MFMA16(a, b, c) __builtin_amdgcn_mfma_f32_16x16x32_bf16((a), (b), (c), 0, 0, 0)

// ---------------------------------------------------------------------------
// Routing: 1 wave = 1 token. Fuses x fp32->bf16 conversion. NO global atomics
// (R2 post-mortem: 8192 atomicAdds to one cache line serialized ~100us at the
// TCC; counting moved to schedule_scatter).
// ---------------------------------------------------------------------------
__global__ __launch_bounds__(256) void routing_kernel(
    const float* __restrict__ x, const float* __restrict__ Wr,
    __bf16* __restrict__ xb, int* __restrict__ top_e, float* __restrict__ top_w)
{
    int wave = threadIdx.x >> 6, lane = threadIdx.x & 63;
    int t = blockIdx.x * 4 + wave;
    const float* xrow = x + (size_t)t * H_DIM;
    __bf16* xbrow = xb + (size_t)t * H_DIM;

    float part[N_EXP];
#pragma unroll
    for (int e = 0; e < N_EXP; ++e) part[e] = 0.f;

#pragma unroll
    for (int half = 0; half < 2; ++half) {
        int h0 = half * 512 + lane * 8;              // wave covers 512 contiguous
        float4 v0 = *(const float4*)(xrow + h0);
        float4 v1 = *(const float4*)(xrow + h0 + 4);
        float xs[8] = {v0.x, v0.y, v0.z, v0.w, v1.x, v1.y, v1.z, v1.w};
        bf16x8 bv;
#pragma unroll
        for (int i = 0; i < 8; ++i) bv[i] = (__bf16)xs[i];
        *(bf16x8*)(xbrow + h0) = bv;                 // 16B/lane, wave-contiguous
#pragma unroll
        for (int i = 0; i < 8; ++i) {
            const float4* wr = (const float4*)(Wr + (size_t)(h0 + i) * N_EXP);
            float4 w0 = wr[0], w1 = wr[1];
            part[0] += xs[i] * w0.x; part[1] += xs[i] * w0.y;
            part[2] += xs[i] * w0.z; part[3] += xs[i] * w0.w;
            part[4] += xs[i] * w1.x; part[5] += xs[i] * w1.y;
            part[6] += xs[i] * w1.z; part[7] += xs[i] * w1.w;
        }
    }
#pragma unroll
    for (int m = 1; m < 64; m <<= 1) {
#pragma unroll
        for (int e = 0; e < N_EXP; ++e) part[e] += __shfl_xor(part[e], m, 64);
    }
    if (lane == 0) {
        float v1 = -1e30f, v2 = -1e30f;
        int i1 = 0, i2 = 0;
#pragma unroll
        for (int e = 0; e < N_EXP; ++e) {
            float p = part[e];
            if (p > v1)      { v2 = v1; i2 = i1; v1 = p; i1 = e; }
            else if (p > v2) { v2 = p;  i2 = e; }
        }
        float w1 = 1.f / (1.f + __expf(v2 - v1));    // normalized top-2; softmax denom cancels
        top_e[t * 2]     = i1;  top_e[t * 2 + 1] = i2;
        top_w[t * 2]     = w1;  top_w[t * 2 + 1] = 1.f - w1;
    }
}

// ---------------------------------------------------------------------------
// Single-block deterministic counting sort (no atomics):
//   phase 1: per-thread register histogram of its 32 assignments
//   phase 2: Hillis-Steele inclusive scan over 256 threads x 8 experts (LDS)
//   phase 3: tid 0 builds expert bases + M-tile worklist
//   phase 4: scatter at precomputed offsets (perm token-sorted per expert)
// ---------------------------------------------------------------------------
__global__ __launch_bounds__(256) void schedule_scatter(
    const int* __restrict__ top_e, const float* __restrict__ top_w,
    int* __restrict__ perm, float* __restrict__ wts,
    int* __restrict__ tile_e, int* __restrict__ tile_m0, int* __restrict__ tile_cnt,
    int* __restrict__ n_tiles)
{
    __shared__ int hist[N_EXP][256];    // 8 KB
    __shared__ int ebase[N_EXP];
    int tid = threadIdx.x;

    int c[N_EXP];
#pragma unroll
    for (int e = 0; e < N_EXP; ++e) c[e] = 0;
    // 32 consecutive assignments per thread (= 16 consecutive tokens)
#pragma unroll 4
    for (int i = 0; i < 32; ++i) {
        int ee = top_e[tid * 32 + i];
#pragma unroll
        for (int e = 0; e < N_EXP; ++e) c[e] += (ee == e);   // predicated, no dyn reg idx
    }
#pragma unroll
    for (int e = 0; e < N_EXP; ++e) hist[e][tid] = c[e];
    __syncthreads();

    // inclusive scan along tid for all 8 experts
    for (int s = 1; s < 256; s <<= 1) {
        int v[N_EXP];
#pragma unroll
        for (int e = 0; e < N_EXP; ++e) v[e] = (tid >= s) ? hist[e][tid - s] : 0;
        __syncthreads();
#pragma unroll
        for (int e = 0; e < N_EXP; ++e) hist[e][tid] += v[e];
        __syncthreads();
    }

    if (tid == 0) {
        int o = 0, nt = 0;
        for (int e = 0; e < N_EXP; ++e) {
            ebase[e] = o;
            int ne = hist[e][255];
            for (int m0 = 0; m0 < ne; m0 += BM) {
                tile_e[nt]   = e;
                tile_m0[nt]  = o + m0;
                tile_cnt[nt] = (ne - m0 < BM) ? (ne - m0) : BM;
                ++nt;
            }
            o += ne;
        }
        *n_tiles = nt;
    }
    __syncthreads();

    // exclusive offset for this thread within each expert, then scatter
#pragma unroll
    for (int e = 0; e < N_EXP; ++e) hist[e][tid] = ebase[e] + hist[e][tid] - c[e];
#pragma unroll 4
    for (int i = 0; i < 32; ++i) {
        int a = tid * 32 + i;
        int e = top_e[a];
        int slot = hist[e][tid]++;      // own column only -- race-free
        perm[slot] = a >> 1;            // token index
        wts[slot]  = top_w[a];
    }
}

// ---------------------------------------------------------------------------
// Convert fp32 weights -> bf16 AND transpose to [N][K] (K-contiguous) so
// MFMA B fragments are 16B LDS vector loads.
//   z in [0,8):   Wg  [H][F] -> Wgt [F][H]
//   z in [8,16):  Wu  [H][F] -> Wut [F][H]
//   z in [16,24): Wd  [F][H] -> Wdt [H][F]
// ---------------------------------------------------------------------------
__global__ __launch_bounds__(256) void transpose_kernel(
    const float* __restrict__ Wg, const float* __restrict__ Wu, const float* __restrict__ Wd,
    __bf16* __restrict__ Wgt, __bf16* __restrict__ Wut, __bf16* __restrict__ Wdt)
{
    int z = blockIdx.z;
    const float* src; __bf16* dst; int R, C;
    if (z < 8)       { src = Wg + (size_t)z * H_DIM * F_DIM;        dst = Wgt + (size_t)z * H_DIM * F_DIM;        R = H_DIM; C = F_DIM; }
    else if (z < 16) { src = Wu + (size_t)(z - 8) * H_DIM * F_DIM;  dst = Wut + (size_t)(z - 8) * H_DIM * F_DIM;  R = H_DIM; C = F_DIM; }
    else             { src = Wd + (size_t)(z - 16) * F_DIM * H_DIM; dst = Wdt + (size_t)(z - 16) * F_DIM * H_DIM; R = F_DIM; C = H_DIM; }
    int c0 = blockIdx.x * 32, r0 = blockIdx.y * 32;
    if (c0 >= C || r0 >= R) return;
    __shared__ float tile[32][33];
    int tx = threadIdx.x & 31, ty = threadIdx.x >> 5;   // 32 x 8
#pragma unroll
    for (int i = 0; i < 4; ++i)
        tile[ty + 8 * i][tx] = src[(size_t)(r0 + ty + 8 * i) * C + c0 + tx];
    __syncthreads();
#pragma unroll
    for (int i = 0; i < 4; ++i)
        dst[(size_t)(c0 + ty + 8 * i) * R + r0 + tx] = (__bf16)tile[tx][ty + 8 * i];
}

// ---------------------------------------------------------------------------
// Grouped GEMM: act[slot][f] = silu(x@Wg) * (x@Wu) * combine_weight.
// Block = 256 thr (4 waves), tile 64(M-rows gathered via perm) x 64(F), K=H.
// Wave w computes 32x32 of gate AND up at (wm,wn).
// ---------------------------------------------------------------------------
__global__ __launch_bounds__(256) void gateup_kernel(
    const __bf16* __restrict__ xb, const __bf16* __restrict__ Wgt, const __bf16* __restrict__ Wut,
    const int* __restrict__ perm, const float* __restrict__ wts,
    const int* __restrict__ tile_e, const int* __restrict__ tile_m0, const int* __restrict__ tile_cnt,
    const int* __restrict__ n_tiles, __bf16* __restrict__ act)
{
    if ((int)blockIdx.x >= *n_tiles) return;
    int e = tile_e[blockIdx.x], m0 = tile_m0[blockIdx.x], mcnt = tile_cnt[blockIdx.x];
    int n0 = blockIdx.y * BN;

    __shared__ __bf16 As[BM][LDK];
    __shared__ __bf16 Bgs[BN][LDK];
    __shared__ __bf16 Bus[BN][LDK];
    __shared__ int   rowtok[BM];
    __shared__ float roww[BM];

    int tid = threadIdx.x;
    if (tid < BM) {
        int slot = m0 + ((tid < mcnt) ? tid : 0);
        rowtok[tid] = perm[slot];
        roww[tid]   = wts[slot];
    }
    __syncthreads();

    const __bf16* Wg_e = Wgt + (size_t)e * F_DIM * H_DIM;
    const __bf16* Wu_e = Wut + (size_t)e * F_DIM * H_DIM;

    int lr = tid >> 3, lc = tid & 7;          // staging: 32 rows x 8 chunks of 16B
    int wave = tid >> 6, lane = tid & 63;
    int wm = wave & 1, wn = wave >> 1;
    int quad = lane >> 4, l16 = lane & 15;

    f32x4 accg[2][2], accu[2][2];
#pragma unroll
    for (int a = 0; a < 2; ++a)
#pragma unroll
        for (int b = 0; b < 2; ++b) {
            accg[a][b] = (f32x4){0.f, 0.f, 0.f, 0.f};
            accu[a][b] = (f32x4){0.f, 0.f, 0.f, 0.f};
        }

    for (int k0 = 0; k0 < H_DIM; k0 += BK) {
#pragma unroll
        for (int p = 0; p < 2; ++p) {
            int r = lr + p * 32;
            *(bf16x8*)&As[r][lc * 8]  = *(const bf16x8*)(xb   + (size_t)rowtok[r] * H_DIM + k0 + lc * 8);
            *(bf16x8*)&Bgs[r][lc * 8] = *(const bf16x8*)(Wg_e + (size_t)(n0 + r) * H_DIM + k0 + lc * 8);
            *(bf16x8*)&Bus[r][lc * 8] = *(const bf16x8*)(Wu_e + (size_t)(n0 + r) * H_DIM + k0 + lc * 8);
        }
        __syncthreads();
#pragma unroll
        for (int kk = 0; kk < BK; kk += 32) {
            int kf = kk + quad * 8;
            bf16x8 a0 = *(const bf16x8*)&As[wm * 32 + l16][kf];
            bf16x8 a1 = *(const bf16x8*)&As[wm * 32 + 16 + l16][kf];
            bf16x8 g0 = *(const bf16x8*)&Bgs[wn * 32 + l16][kf];
            bf16x8 g1 = *(const bf16x8*)&Bgs[wn * 32 + 16 + l16][kf];
            bf16x8 u0 = *(const bf16x8*)&Bus[wn * 32 + l16][kf];
            bf16x8 u1 = *(const bf16x8*)&Bus[wn * 32 + 16 + l16][kf];
            accg[0][0] = MFMA16(a0, g0, accg[0][0]);
            accg[0][1] = MFMA16(a0, g1, accg[0][1]);
            accg[1][0] = MFMA16(a1, g0, accg[1][0]);
            accg[1][1] = MFMA16(a1, g1, accg[1][1]);
            accu[0][0] = MFMA16(a0, u0, accu[0][0]);
            accu[0][1] = MFMA16(a0, u1, accu[0][1]);
            accu[1][0] = MFMA16(a1, u0, accu[1][0]);
            accu[1][1] = MFMA16(a1, u1, accu[1][1]);
        }
        __syncthreads();
    }

    // Epilogue: C/D layout col=lane&15, row=quad*4+reg (m89-verified).
#pragma unroll
    for (int im = 0; im < 2; ++im) {
#pragma unroll
        for (int in = 0; in < 2; ++in) {
            int col = n0 + wn * 32 + in * 16 + l16;
#pragma unroll
            for (int r = 0; r < 4; ++r) {
                int rl = wm * 32 + im * 16 + quad * 4 + r;
                if (rl < mcnt) {
                    float g = accg[im][in][r];
                    float u = accu[im][in][r];
                    float s = g / (1.f + __expf(-g));         // silu
                    act[(size_t)(m0 + rl) * F_DIM + col] = (__bf16)(s * u * roww[rl]);
                }
            }
        }
    }
}

// ---------------------------------------------------------------------------
// Grouped down-proj: out[token][h] += act[slot][:] @ Wd[e][:][h]
// (combine weight already folded into act). fp32 native atomics, 2 writers max.
// ---------------------------------------------------------------------------
__global__ __launch_bounds__(256) void down_kernel(
    const __bf16* __restrict__ act, const __bf16* __restrict__ Wdt,
    const int* __restrict__ perm,
    const int* __restrict__ tile_e, const int* __restrict__ tile_m0, const int* __restrict__ tile_cnt,
    const int* __restrict__ n_tiles, float* __restrict__ out)
{
    if ((int)blockIdx.x >= *n_tiles) return;
    int e = tile_e[blockIdx.x], m0 = tile_m0[blockIdx.x], mcnt = tile_cnt[blockIdx.x];
    int n0 = blockIdx.y * BN;

    __shared__ __bf16 As[BM][LDK];
    __shared__ __bf16 Bs[BN][LDK];
    __shared__ int rowtok[BM];

    int tid = threadIdx.x;
    if (tid < BM) rowtok[tid] = perm[m0 + ((tid < mcnt) ? tid : 0)];
    __syncthreads();

    const __bf16* Wd_e = Wdt + (size_t)e * H_DIM * F_DIM;
    int lr = tid >> 3, lc = tid & 7;
    int wave = tid >> 6, lane = tid & 63;
    int wm = wave & 1, wn = wave >> 1;
    int quad = lane >> 4, l16 = lane & 15;

    f32x4 acc[2][2];
#pragma unroll
    for (int a = 0; a < 2; ++a)
#pragma unroll
        for (int b = 0; b < 2; ++b) acc[a][b] = (f32x4){0.f, 0.f, 0.f, 0.f};

    for (int k0 = 0; k0 < F_DIM; k0 += BK) {
#pragma unroll
        for (int p = 0; p < 2; ++p) {
            int r = lr + p * 32;
            int ar = m0 + ((r < mcnt) ? r : 0);
            *(bf16x8*)&As[r][lc * 8] = *(const bf16x8*)(act  + (size_t)ar * F_DIM + k0 + lc * 8);
            *(bf16x8*)&Bs[r][lc * 8] = *(const bf16x8*)(Wd_e + (size_t)(n0 + r) * F_DIM + k0 + lc * 8);
        }
        __syncthreads();
#pragma unroll
        for (int kk = 0; kk < BK; kk += 32) {
            int kf = kk + quad * 8;
            bf16x8 a0 = *(const bf16x8*)&As[wm * 32 + l16][kf];
            bf16x8 a1 = *(const bf16x8*)&As[wm * 32 + 16 + l16][kf];
            bf16x8 b0 = *(const bf16x8*)&Bs[wn * 32 + l16][kf];
            bf16x8 b1 = *(const bf16x8*)&Bs[wn * 32 + 16 + l16][kf];
            acc[0][0] = MFMA16(a0, b0, acc[0][0]);
            acc[0][1] = MFMA16(a0, b1, acc[0][1]);
            acc[1][0] = MFMA16(a1, b0, acc[1][0]);
            acc[1][1] = MFMA16(a1, b1, acc[1][1]);
        }
        __syncthreads();
    }

#pragma unroll
    for (int im = 0; im < 2; ++im) {
#pragma unroll
        for (int in = 0; in < 2; ++in) {
            int col = n0 + wn * 32 + in * 16 + l16;
#pragma unroll
            for (int r = 0; r < 4; ++r) {
                int rl = wm * 32 + im * 16 + quad * 4 + r;
                if (rl < mcnt)
                    unsafeAtomicAdd(out + (size_t)rowtok[rl] * H_DIM + col, acc[im][in][r]);
            }
        }
    }
}

// ---------------------------------------------------------------------------
extern "C" void kernel_launch(void* const* d_in, const int* in_sizes, int n_in,
                              void* d_out, int out_size, void* d_ws, size_t ws_size,
                              hipStream_t stream)
{
    const float* x  = (const float*)d_in[0];
    const float* Wr = (const float*)d_in[1];
    const float* Wg = (const float*)d_in[2];
    const float* Wu = (const float*)d_in[3];
    const float* Wd = (const float*)d_in[4];
    float* out = (float*)d_out;

    char* ws = (char*)d_ws;
    size_t off = 0;
    auto carve = [&](size_t bytes) {
        char* p = ws + off;
        off = (off + bytes + 255) & ~(size_t)255;
        return p;
    };
    __bf16* xb   = (__bf16*)carve((size_t)T_TOK * H_DIM * 2);            // 8 MB
    __bf16* Wgt  = (__bf16*)carve((size_t)N_EXP * H_DIM * F_DIM * 2);    // 8 MB
    __bf16* Wut  = (__bf16*)carve((size_t)N_EXP * H_DIM * F_DIM * 2);    // 8 MB
    __bf16* Wdt  = (__bf16*)carve((size_t)N_EXP * H_DIM * F_DIM * 2);    // 8 MB
    __bf16* act  = (__bf16*)carve((size_t)N_ASSIGN * F_DIM * 2);         // 8 MB
    int*   top_e = (int*)carve((size_t)T_TOK * 2 * sizeof(int));
    float* top_w = (float*)carve((size_t)T_TOK * 2 * sizeof(float));
    int*   perm  = (int*)carve((size_t)N_ASSIGN * sizeof(int));
    float* wts   = (float*)carve((size_t)N_ASSIGN * sizeof(float));
    int*   tl_e  = (int*)carve(MAX_TILES * sizeof(int));
    int*   tl_m0 = (int*)carve(MAX_TILES * sizeof(int));
    int*   tl_cn = (int*)carve(MAX_TILES * sizeof(int));
    int*   n_til = (int*)carve(sizeof(int));

    hipMemsetAsync(d_out, 0, (size_t)out_size * sizeof(float), stream);

    routing_kernel<<<T_TOK / 4, 256, 0, stream>>>(x, Wr, xb, top_e, top_w);
    schedule_scatter<<<1, 256, 0, stream>>>(top_e, top_w, perm, wts,
                                            tl_e, tl_m0, tl_cn, n_til);
    transpose_kernel<<<dim3(32, 32, 24), 256, 0, stream>>>(Wg, Wu, Wd, Wgt, Wut, Wdt);
    gateup_kernel<<<dim3(GRID_MT, F_DIM / BN), 256, 0, stream>>>(
        xb, Wgt, Wut, perm, wts, tl_e, tl_m0, tl_cn, n_til, act);
    down_kernel<<<dim3(GRID_MT, H_DIM / BN), 256, 0, stream>>>(
        act, Wdt, perm, tl_e, tl_m0, tl_cn, n_til, out);
}